// Round 8
// baseline (1306.503 us; speedup 1.0000x reference)
//
#include <hip/hip_runtime.h>

#define F 128
#define SCAN_T 256
#define SCAN_ELEMS 16
#define SCAN_CHUNK (SCAN_T * SCAN_ELEMS)   // 4096 per scan block

#define EB_LOG   12
#define EB_CHUNK 4096                      // edges per partition block
#define BK_SHIFT 6
#define BK_NODES 64                        // nodes per bucket
#define P_MAX    2048                      // max buckets (N <= 131072)

static inline int align4i(int n) { return (n + 3) & ~3; }

// ---- pass A: per-block LDS histogram over dst buckets --------------------
__global__ void part_hist(const int* __restrict__ dst, int* __restrict__ counts_T,
                          int E, int nblkA, int P) {
    __shared__ int hist[P_MAX];
    int b = blockIdx.x, tid = threadIdx.x;
    for (int i = tid; i < P; i += 256) hist[i] = 0;
    __syncthreads();
    int base_e = b << EB_LOG;
#pragma unroll
    for (int q = 0; q < 4; ++q) {
        int i = base_e + (q * 256 + tid) * 4;
        if (i + 3 < E) {
            int4 d = *(const int4*)&dst[i];
            atomicAdd(&hist[d.x >> BK_SHIFT], 1);
            atomicAdd(&hist[d.y >> BK_SHIFT], 1);
            atomicAdd(&hist[d.z >> BK_SHIFT], 1);
            atomicAdd(&hist[d.w >> BK_SHIFT], 1);
        } else {
            for (int k = i; k < E && k < i + 4; ++k)
                atomicAdd(&hist[dst[k] >> BK_SHIFT], 1);
        }
    }
    __syncthreads();
    for (int i = tid; i < P; i += 256) counts_T[i * nblkA + b] = hist[i];
}

// ---- 3-level scan (proven) ----------------------------------------------
__global__ void scan_partial(const int* __restrict__ deg, int* __restrict__ bsum, int M) {
    int base = blockIdx.x * SCAN_CHUNK + threadIdx.x * SCAN_ELEMS;
    int s = 0;
    if (base + SCAN_ELEMS - 1 < M) {
#pragma unroll
        for (int q = 0; q < SCAN_ELEMS / 4; ++q) {
            int4 v = *(const int4*)&deg[base + q * 4];
            s += v.x + v.y + v.z + v.w;
        }
    } else {
        for (int i = base; i < M; ++i) s += deg[i];
    }
    for (int off = 32; off; off >>= 1) s += __shfl_down(s, off);
    __shared__ int wt[4];
    int wid = threadIdx.x >> 6;
    if ((threadIdx.x & 63) == 0) wt[wid] = s;
    __syncthreads();
    if (threadIdx.x == 0) bsum[blockIdx.x] = wt[0] + wt[1] + wt[2] + wt[3];
}

__global__ void __launch_bounds__(1024)
scan_mid(const int* __restrict__ bsum, int* __restrict__ bpref,
         int* __restrict__ offs, int nB, int M) {
    __shared__ int sh[1024];
    int t = threadIdx.x;
    int v = (t < nB) ? bsum[t] : 0;
    sh[t] = v;
    __syncthreads();
    for (int off = 1; off < 1024; off <<= 1) {
        int u = (t >= off) ? sh[t - off] : 0;
        __syncthreads();
        sh[t] += u;
        __syncthreads();
    }
    if (t < nB) bpref[t] = sh[t] - v;          // exclusive
    if (t == 1023) offs[M] = sh[1023];         // total = E
}

__global__ void scan_write(const int* __restrict__ deg, const int* __restrict__ bpref,
                           int* __restrict__ offs, int* __restrict__ cursor, int M) {
    int tid = threadIdx.x;
    int base = blockIdx.x * SCAN_CHUNK + tid * SCAN_ELEMS;
    int v[SCAN_ELEMS];
    int s = 0;
    bool full = (base + SCAN_ELEMS - 1 < M);
    if (full) {
#pragma unroll
        for (int q = 0; q < SCAN_ELEMS / 4; ++q) {
            int4 w = *(const int4*)&deg[base + q * 4];
            v[q * 4 + 0] = w.x; v[q * 4 + 1] = w.y; v[q * 4 + 2] = w.z; v[q * 4 + 3] = w.w;
            s += w.x + w.y + w.z + w.w;
        }
    } else {
#pragma unroll
        for (int k = 0; k < SCAN_ELEMS; ++k) {
            int i = base + k;
            v[k] = (i < M) ? deg[i] : 0;
            s += v[k];
        }
    }
    int inc = s;
    int lane = tid & 63, wid = tid >> 6;
    for (int off = 1; off < 64; off <<= 1) {
        int u = __shfl_up(inc, off);
        if (lane >= off) inc += u;
    }
    __shared__ int wt[4];
    if (lane == 63) wt[wid] = inc;
    __syncthreads();
    int wbase = 0;
    for (int w = 0; w < wid; ++w) wbase += wt[w];
    int run = bpref[blockIdx.x] + wbase + (inc - s);
    if (full) {
#pragma unroll
        for (int q = 0; q < SCAN_ELEMS / 4; ++q) {
            int4 r;
            r.x = run; run += v[q * 4 + 0];
            r.y = run; run += v[q * 4 + 1];
            r.z = run; run += v[q * 4 + 2];
            r.w = run; run += v[q * 4 + 3];
            *(int4*)&offs[base + q * 4] = r;
            if (cursor) *(int4*)&cursor[base + q * 4] = r;
        }
    } else {
#pragma unroll
        for (int k = 0; k < SCAN_ELEMS; ++k) {
            int i = base + k;
            if (i < M) {
                offs[i] = run;
                if (cursor) cursor[i] = run;
                run += v[k];
            }
        }
    }
}

// ---- pass C: place packed edges grouped by bucket (LDS ranks only) -------
__global__ void part_scatter(const int* __restrict__ src, const int* __restrict__ dst,
                             const int* __restrict__ offs2, int* __restrict__ ebuf,
                             int E, int nblkA, int P) {
    __shared__ int hist[P_MAX];
    __shared__ int base[P_MAX];
    int b = blockIdx.x, tid = threadIdx.x;
    for (int i = tid; i < P; i += 256) {
        hist[i] = 0;
        base[i] = offs2[i * nblkA + b];
    }
    __syncthreads();
    int base_e = b << EB_LOG;
#pragma unroll
    for (int q = 0; q < 4; ++q) {
        int i = base_e + (q * 256 + tid) * 4;
        if (i + 3 < E) {
            int4 s = *(const int4*)&src[i];
            int4 d = *(const int4*)&dst[i];
            int bk, r;
            bk = d.x >> BK_SHIFT; r = atomicAdd(&hist[bk], 1);
            ebuf[base[bk] + r] = (s.x << BK_SHIFT) | (d.x & (BK_NODES - 1));
            bk = d.y >> BK_SHIFT; r = atomicAdd(&hist[bk], 1);
            ebuf[base[bk] + r] = (s.y << BK_SHIFT) | (d.y & (BK_NODES - 1));
            bk = d.z >> BK_SHIFT; r = atomicAdd(&hist[bk], 1);
            ebuf[base[bk] + r] = (s.z << BK_SHIFT) | (d.z & (BK_NODES - 1));
            bk = d.w >> BK_SHIFT; r = atomicAdd(&hist[bk], 1);
            ebuf[base[bk] + r] = (s.w << BK_SHIFT) | (d.w & (BK_NODES - 1));
        } else {
            for (int k = i; k < E && k < i + 4; ++k) {
                int bk = dst[k] >> BK_SHIFT;
                int r = atomicAdd(&hist[bk], 1);
                ebuf[base[bk] + r] = (src[k] << BK_SHIFT) | (dst[k] & (BK_NODES - 1));
            }
        }
    }
}

// ---- phase 2: per-bucket LDS accumulate + relu ---------------------------
// acc layout [4][BK_NODES][32] floats: ds_add lanes hit consecutive banks.
__global__ void bucket_accum(const float* __restrict__ x, const int* __restrict__ offs2,
                             const int* __restrict__ ebuf, float* __restrict__ out,
                             int N, int nblkA) {
    __shared__ float acc[4 * BK_NODES * 32];   // 32 KB
    int p = blockIdx.x, tid = threadIdx.x;
    int node_base = p << BK_SHIFT;
    int nrows = N - node_base; if (nrows > BK_NODES) nrows = BK_NODES;
    const float4* x4 = (const float4*)x;

    // init with x rows (self-loop term)
    for (int slot = tid; slot < BK_NODES * 32; slot += 256) {
        int r = slot >> 5, c = slot & 31;
        if (r < nrows) {
            float4 v = x4[(node_base + r) * 32 + c];
            acc[0 * 2048 + slot] = v.x;
            acc[1 * 2048 + slot] = v.y;
            acc[2 * 2048 + slot] = v.z;
            acc[3 * 2048 + slot] = v.w;
        }
    }
    __syncthreads();

    int begin = offs2[p * nblkA];
    int end   = offs2[(p + 1) * nblkA];
    int g = tid >> 5, c = tid & 31;
    int e = begin + g;
    // unroll-4: 4 independent row gathers in flight per 32-lane group
    for (; e + 24 < end; e += 32) {
        int p0 = ebuf[e], p1 = ebuf[e + 8], p2 = ebuf[e + 16], p3 = ebuf[e + 24];
        float4 v0 = x4[(p0 >> BK_SHIFT) * 32 + c];
        float4 v1 = x4[(p1 >> BK_SHIFT) * 32 + c];
        float4 v2 = x4[(p2 >> BK_SHIFT) * 32 + c];
        float4 v3 = x4[(p3 >> BK_SHIFT) * 32 + c];
        int l0 = (p0 & (BK_NODES - 1)) * 32 + c;
        int l1 = (p1 & (BK_NODES - 1)) * 32 + c;
        int l2 = (p2 & (BK_NODES - 1)) * 32 + c;
        int l3 = (p3 & (BK_NODES - 1)) * 32 + c;
        atomicAdd(&acc[l0], v0.x); atomicAdd(&acc[2048 + l0], v0.y);
        atomicAdd(&acc[4096 + l0], v0.z); atomicAdd(&acc[6144 + l0], v0.w);
        atomicAdd(&acc[l1], v1.x); atomicAdd(&acc[2048 + l1], v1.y);
        atomicAdd(&acc[4096 + l1], v1.z); atomicAdd(&acc[6144 + l1], v1.w);
        atomicAdd(&acc[l2], v2.x); atomicAdd(&acc[2048 + l2], v2.y);
        atomicAdd(&acc[4096 + l2], v2.z); atomicAdd(&acc[6144 + l2], v2.w);
        atomicAdd(&acc[l3], v3.x); atomicAdd(&acc[2048 + l3], v3.y);
        atomicAdd(&acc[4096 + l3], v3.z); atomicAdd(&acc[6144 + l3], v3.w);
    }
    for (; e < end; e += 8) {
        int pk = ebuf[e];
        float4 v = x4[(pk >> BK_SHIFT) * 32 + c];
        int l = (pk & (BK_NODES - 1)) * 32 + c;
        atomicAdd(&acc[l], v.x); atomicAdd(&acc[2048 + l], v.y);
        atomicAdd(&acc[4096 + l], v.z); atomicAdd(&acc[6144 + l], v.w);
    }
    __syncthreads();

    // relu + writeback
    float4* o4 = (float4*)out;
    for (int slot = tid; slot < BK_NODES * 32; slot += 256) {
        int r = slot >> 5, c2 = slot & 31;
        if (r < nrows) {
            float4 v;
            v.x = fmaxf(acc[slot], 0.f);
            v.y = fmaxf(acc[2048 + slot], 0.f);
            v.z = fmaxf(acc[4096 + slot], 0.f);
            v.w = fmaxf(acc[6144 + slot], 0.f);
            o4[(node_base + r) * 32 + c2] = v;
        }
    }
}

// ---- fallback path kernels (B=1 cursor CSR + gather), proven round 3-5 ---
__global__ void hist_kernel(const int* __restrict__ dst, int* __restrict__ deg, int E) {
    int i = (blockIdx.x * blockDim.x + threadIdx.x) * 4;
    if (i + 3 < E) {
        int4 d = *(const int4*)&dst[i];
        atomicAdd(&deg[d.x], 1); atomicAdd(&deg[d.y], 1);
        atomicAdd(&deg[d.z], 1); atomicAdd(&deg[d.w], 1);
    } else {
        for (int k = i; k < E; ++k) atomicAdd(&deg[dst[k]], 1);
    }
}

__global__ void reorder_kernel(const int* __restrict__ src, const int* __restrict__ dst,
                               int* __restrict__ cursor, int* __restrict__ csr_src, int E) {
    int i = (blockIdx.x * blockDim.x + threadIdx.x) * 4;
    if (i + 3 < E) {
        int4 s = *(const int4*)&src[i];
        int4 d = *(const int4*)&dst[i];
        csr_src[atomicAdd(&cursor[d.x], 1)] = s.x;
        csr_src[atomicAdd(&cursor[d.y], 1)] = s.y;
        csr_src[atomicAdd(&cursor[d.z], 1)] = s.z;
        csr_src[atomicAdd(&cursor[d.w], 1)] = s.w;
    } else {
        for (int k = i; k < E; ++k) csr_src[atomicAdd(&cursor[dst[k]], 1)] = src[k];
    }
}

__global__ void gather_kernel(const float* __restrict__ x, const int* __restrict__ offs,
                              const int* __restrict__ csr_src, float* __restrict__ out, int N) {
    int t = blockIdx.x * blockDim.x + threadIdx.x;
    int node = t >> 5;
    if (node >= N) return;
    int c = t & 31;
    const float4* x4 = (const float4*)x;
    float4 acc = x4[node * 32 + c];
    int b = offs[node], e = offs[node + 1];
    int j = b;
    for (; j + 3 < e; j += 4) {
        int s0 = csr_src[j], s1 = csr_src[j + 1], s2 = csr_src[j + 2], s3 = csr_src[j + 3];
        float4 v0 = x4[s0 * 32 + c], v1 = x4[s1 * 32 + c], v2 = x4[s2 * 32 + c], v3 = x4[s3 * 32 + c];
        acc.x += (v0.x + v1.x) + (v2.x + v3.x);
        acc.y += (v0.y + v1.y) + (v2.y + v3.y);
        acc.z += (v0.z + v1.z) + (v2.z + v3.z);
        acc.w += (v0.w + v1.w) + (v2.w + v3.w);
    }
    for (; j < e; ++j) {
        int s = csr_src[j];
        float4 v = x4[s * 32 + c];
        acc.x += v.x; acc.y += v.y; acc.z += v.z; acc.w += v.w;
    }
    acc.x = fmaxf(acc.x, 0.f); acc.y = fmaxf(acc.y, 0.f);
    acc.z = fmaxf(acc.z, 0.f); acc.w = fmaxf(acc.w, 0.f);
    ((float4*)out)[node * 32 + c] = acc;
}

// ---- launch --------------------------------------------------------------
extern "C" void kernel_launch(void* const* d_in, const int* in_sizes, int n_in,
                              void* d_out, int out_size, void* d_ws, size_t ws_size,
                              hipStream_t stream) {
    const float* x  = (const float*)d_in[0];
    const int*   ei = (const int*)d_in[1];     // [2, E]: src row then dst row
    float* out = (float*)d_out;

    int N = in_sizes[0] / F;          // 100000
    int E = in_sizes[1] / 2;          // 1600000
    const int* src = ei;
    const int* dst = ei + E;

    int P = (N + BK_NODES - 1) >> BK_SHIFT;            // 1563
    int nblkA = (E + EB_CHUNK - 1) >> EB_LOG;          // 391
    int M2 = P * nblkA;                                // 611133

    char* ws = (char*)d_ws;
    int* counts_T = (int*)ws;                          // M2
    int* offs2    = counts_T + align4i(M2);            // M2+1
    int* ebuf     = offs2 + align4i(M2 + 1);           // E
    int* bsum     = ebuf + align4i(E);                 // 1024
    int* bpref    = bsum + 1024;                       // 1024
    size_t need = (size_t)((char*)(bpref + 1024) - ws);

    if (P <= P_MAX && ws_size >= need) {
        int nB = (M2 + SCAN_CHUNK - 1) / SCAN_CHUNK;   // 150 (<=1024)
        part_hist<<<nblkA, 256, 0, stream>>>(dst, counts_T, E, nblkA, P);
        scan_partial<<<nB, SCAN_T, 0, stream>>>(counts_T, bsum, M2);
        scan_mid<<<1, 1024, 0, stream>>>(bsum, bpref, offs2, nB, M2);
        scan_write<<<nB, SCAN_T, 0, stream>>>(counts_T, bpref, offs2, nullptr, M2);
        part_scatter<<<nblkA, 256, 0, stream>>>(src, dst, offs2, ebuf, E, nblkA, P);
        bucket_accum<<<P, 256, 0, stream>>>(x, offs2, ebuf, out, N, nblkA);
    } else {
        // fallback: B=1 cursor CSR + gather
        int* deg     = (int*)ws;                       // N
        int* offs    = deg + align4i(N);               // N+1
        int* csr_src = offs + align4i(N + 1);          // E
        int* cursor  = csr_src + align4i(E);           // N
        int* fb_bsum = cursor + align4i(N);
        int* fb_bpref = fb_bsum + 1024;
        int nB = (N + SCAN_CHUNK - 1) / SCAN_CHUNK;
        int eb = (E / 4 + 255) / 256 + 1;
        hipMemsetAsync(deg, 0, (size_t)N * sizeof(int), stream);
        hist_kernel<<<eb, 256, 0, stream>>>(dst, deg, E);
        scan_partial<<<nB, SCAN_T, 0, stream>>>(deg, fb_bsum, N);
        scan_mid<<<1, 1024, 0, stream>>>(fb_bsum, fb_bpref, offs, nB, N);
        scan_write<<<nB, SCAN_T, 0, stream>>>(deg, fb_bpref, offs, cursor, N);
        reorder_kernel<<<eb, 256, 0, stream>>>(src, dst, cursor, csr_src, E);
        int gth = N * 32;
        gather_kernel<<<(gth + 255) / 256, 256, 0, stream>>>(x, offs, csr_src, out, N);
    }
}

// Round 9
// 257.703 us; speedup vs baseline: 5.0698x; 5.0698x over previous
//
#include <hip/hip_runtime.h>

#define F 128
#define SCAN_T 256
#define SCAN_ELEMS 16
#define SCAN_CHUNK (SCAN_T * SCAN_ELEMS)   // 4096 per scan block

#define EB_LOG   12
#define EB_CHUNK 4096                      // edges per partition block
#define BK_SHIFT 6
#define BK_NODES 64                        // nodes per bucket
#define P_MAX    2048                      // max buckets (N <= 131072)

static inline int align4i(int n) { return (n + 3) & ~3; }

// ---- pass A: per-block LDS histogram over dst buckets (validated ~25us) --
__global__ void part_hist(const int* __restrict__ dst, int* __restrict__ counts_T,
                          int E, int nblkA, int P) {
    __shared__ int hist[P_MAX];
    int b = blockIdx.x, tid = threadIdx.x;
    for (int i = tid; i < P; i += 256) hist[i] = 0;
    __syncthreads();
    int base_e = b << EB_LOG;
#pragma unroll
    for (int q = 0; q < 4; ++q) {
        int i = base_e + (q * 256 + tid) * 4;
        if (i + 3 < E) {
            int4 d = *(const int4*)&dst[i];
            atomicAdd(&hist[d.x >> BK_SHIFT], 1);
            atomicAdd(&hist[d.y >> BK_SHIFT], 1);
            atomicAdd(&hist[d.z >> BK_SHIFT], 1);
            atomicAdd(&hist[d.w >> BK_SHIFT], 1);
        } else {
            for (int k = i; k < E && k < i + 4; ++k)
                atomicAdd(&hist[dst[k] >> BK_SHIFT], 1);
        }
    }
    __syncthreads();
    for (int i = tid; i < P; i += 256) counts_T[i * nblkA + b] = hist[i];
}

// ---- 3-level scan (proven) ----------------------------------------------
__global__ void scan_partial(const int* __restrict__ deg, int* __restrict__ bsum, int M) {
    int base = blockIdx.x * SCAN_CHUNK + threadIdx.x * SCAN_ELEMS;
    int s = 0;
    if (base + SCAN_ELEMS - 1 < M) {
#pragma unroll
        for (int q = 0; q < SCAN_ELEMS / 4; ++q) {
            int4 v = *(const int4*)&deg[base + q * 4];
            s += v.x + v.y + v.z + v.w;
        }
    } else {
        for (int i = base; i < M; ++i) s += deg[i];
    }
    for (int off = 32; off; off >>= 1) s += __shfl_down(s, off);
    __shared__ int wt[4];
    int wid = threadIdx.x >> 6;
    if ((threadIdx.x & 63) == 0) wt[wid] = s;
    __syncthreads();
    if (threadIdx.x == 0) bsum[blockIdx.x] = wt[0] + wt[1] + wt[2] + wt[3];
}

__global__ void __launch_bounds__(1024)
scan_mid(const int* __restrict__ bsum, int* __restrict__ bpref,
         int* __restrict__ offs, int nB, int M) {
    __shared__ int sh[1024];
    int t = threadIdx.x;
    int v = (t < nB) ? bsum[t] : 0;
    sh[t] = v;
    __syncthreads();
    for (int off = 1; off < 1024; off <<= 1) {
        int u = (t >= off) ? sh[t - off] : 0;
        __syncthreads();
        sh[t] += u;
        __syncthreads();
    }
    if (t < nB) bpref[t] = sh[t] - v;          // exclusive
    if (t == 1023) offs[M] = sh[1023];         // total = E
}

__global__ void scan_write(const int* __restrict__ deg, const int* __restrict__ bpref,
                           int* __restrict__ offs, int* __restrict__ cursor, int M) {
    int tid = threadIdx.x;
    int base = blockIdx.x * SCAN_CHUNK + tid * SCAN_ELEMS;
    int v[SCAN_ELEMS];
    int s = 0;
    bool full = (base + SCAN_ELEMS - 1 < M);
    if (full) {
#pragma unroll
        for (int q = 0; q < SCAN_ELEMS / 4; ++q) {
            int4 w = *(const int4*)&deg[base + q * 4];
            v[q * 4 + 0] = w.x; v[q * 4 + 1] = w.y; v[q * 4 + 2] = w.z; v[q * 4 + 3] = w.w;
            s += w.x + w.y + w.z + w.w;
        }
    } else {
#pragma unroll
        for (int k = 0; k < SCAN_ELEMS; ++k) {
            int i = base + k;
            v[k] = (i < M) ? deg[i] : 0;
            s += v[k];
        }
    }
    int inc = s;
    int lane = tid & 63, wid = tid >> 6;
    for (int off = 1; off < 64; off <<= 1) {
        int u = __shfl_up(inc, off);
        if (lane >= off) inc += u;
    }
    __shared__ int wt[4];
    if (lane == 63) wt[wid] = inc;
    __syncthreads();
    int wbase = 0;
    for (int w = 0; w < wid; ++w) wbase += wt[w];
    int run = bpref[blockIdx.x] + wbase + (inc - s);
    if (full) {
#pragma unroll
        for (int q = 0; q < SCAN_ELEMS / 4; ++q) {
            int4 r;
            r.x = run; run += v[q * 4 + 0];
            r.y = run; run += v[q * 4 + 1];
            r.z = run; run += v[q * 4 + 2];
            r.w = run; run += v[q * 4 + 3];
            *(int4*)&offs[base + q * 4] = r;
            if (cursor) *(int4*)&cursor[base + q * 4] = r;
        }
    } else {
#pragma unroll
        for (int k = 0; k < SCAN_ELEMS; ++k) {
            int i = base + k;
            if (i < M) {
                offs[i] = run;
                if (cursor) cursor[i] = run;
                run += v[k];
            }
        }
    }
}

// ---- pass C: place packed edges grouped by bucket (LDS ranks only) -------
__global__ void part_scatter(const int* __restrict__ src, const int* __restrict__ dst,
                             const int* __restrict__ offs2, int* __restrict__ ebuf,
                             int E, int nblkA, int P) {
    __shared__ int hist[P_MAX];
    __shared__ int base[P_MAX];
    int b = blockIdx.x, tid = threadIdx.x;
    for (int i = tid; i < P; i += 256) {
        hist[i] = 0;
        base[i] = offs2[i * nblkA + b];
    }
    __syncthreads();
    int base_e = b << EB_LOG;
#pragma unroll
    for (int q = 0; q < 4; ++q) {
        int i = base_e + (q * 256 + tid) * 4;
        if (i + 3 < E) {
            int4 s = *(const int4*)&src[i];
            int4 d = *(const int4*)&dst[i];
            int bk, r;
            bk = d.x >> BK_SHIFT; r = atomicAdd(&hist[bk], 1);
            ebuf[base[bk] + r] = (s.x << BK_SHIFT) | (d.x & (BK_NODES - 1));
            bk = d.y >> BK_SHIFT; r = atomicAdd(&hist[bk], 1);
            ebuf[base[bk] + r] = (s.y << BK_SHIFT) | (d.y & (BK_NODES - 1));
            bk = d.z >> BK_SHIFT; r = atomicAdd(&hist[bk], 1);
            ebuf[base[bk] + r] = (s.z << BK_SHIFT) | (d.z & (BK_NODES - 1));
            bk = d.w >> BK_SHIFT; r = atomicAdd(&hist[bk], 1);
            ebuf[base[bk] + r] = (s.w << BK_SHIFT) | (d.w & (BK_NODES - 1));
        } else {
            for (int k = i; k < E && k < i + 4; ++k) {
                int bk = dst[k] >> BK_SHIFT;
                int r = atomicAdd(&hist[bk], 1);
                ebuf[base[bk] + r] = (src[k] << BK_SHIFT) | (dst[k] & (BK_NODES - 1));
            }
        }
    }
}

// ---- pass D (new): per-bucket LDS node-sort -> per-node CSR --------------
// One block per bucket. Stream the bucket's packed edges twice: (1) 64-entry
// LDS histogram, (2) LDS-cursor placement. Emits offs[N+1] and csr_src[E]
// for the proven register-accumulate gather. No global atomics, no edge
// storage in LDS (keeps occupancy high).
__global__ void bucket_csr(const int* __restrict__ ebuf, const int* __restrict__ offs2,
                           int* __restrict__ offs, int* __restrict__ csr_src,
                           int N, int E, int nblkA) {
    __shared__ int hist[BK_NODES];
    __shared__ int cur[BK_NODES];
    int p = blockIdx.x, tid = threadIdx.x;
    int node_base = p << BK_SHIFT;
    int nrows = N - node_base; if (nrows > BK_NODES) nrows = BK_NODES;
    int b0 = offs2[p * nblkA];
    int b1 = offs2[(p + 1) * nblkA];          // offs2[M2] = E for the last bucket
    if (tid < BK_NODES) hist[tid] = 0;
    __syncthreads();
    for (int i = b0 + tid; i < b1; i += 256)
        atomicAdd(&hist[ebuf[i] & (BK_NODES - 1)], 1);
    __syncthreads();
    if (tid < BK_NODES) {                      // wave 0: exclusive scan of 64
        int v = hist[tid];
        int inc = v;
        for (int off = 1; off < 64; off <<= 1) {
            int u = __shfl_up(inc, off);
            if (tid >= off) inc += u;
        }
        int ex = inc - v;
        cur[tid] = ex;
        if (tid < nrows) offs[node_base + tid] = b0 + ex;
    }
    __syncthreads();
    for (int i = b0 + tid; i < b1; i += 256) {
        int pk = ebuf[i];
        int r = atomicAdd(&cur[pk & (BK_NODES - 1)], 1);
        csr_src[b0 + r] = pk >> BK_SHIFT;      // placement within 4KB window: L2-local
    }
    if (p == 0 && tid == 0) offs[N] = E;
}

// ---- phase 2: proven register-accumulate gather + self-loop + relu -------
__global__ void gather_kernel(const float* __restrict__ x, const int* __restrict__ offs,
                              const int* __restrict__ csr_src, float* __restrict__ out, int N) {
    int t = blockIdx.x * blockDim.x + threadIdx.x;
    int node = t >> 5;
    if (node >= N) return;
    int c = t & 31;
    const float4* x4 = (const float4*)x;
    float4 acc = x4[node * 32 + c];            // self-loop term
    int b = offs[node], e = offs[node + 1];
    int j = b;
    for (; j + 7 < e; j += 8) {
        int s0 = csr_src[j + 0], s1 = csr_src[j + 1], s2 = csr_src[j + 2], s3 = csr_src[j + 3];
        int s4 = csr_src[j + 4], s5 = csr_src[j + 5], s6 = csr_src[j + 6], s7 = csr_src[j + 7];
        float4 v0 = x4[s0 * 32 + c], v1 = x4[s1 * 32 + c], v2 = x4[s2 * 32 + c], v3 = x4[s3 * 32 + c];
        float4 v4 = x4[s4 * 32 + c], v5 = x4[s5 * 32 + c], v6 = x4[s6 * 32 + c], v7 = x4[s7 * 32 + c];
        acc.x += (v0.x + v1.x) + (v2.x + v3.x) + ((v4.x + v5.x) + (v6.x + v7.x));
        acc.y += (v0.y + v1.y) + (v2.y + v3.y) + ((v4.y + v5.y) + (v6.y + v7.y));
        acc.z += (v0.z + v1.z) + (v2.z + v3.z) + ((v4.z + v5.z) + (v6.z + v7.z));
        acc.w += (v0.w + v1.w) + (v2.w + v3.w) + ((v4.w + v5.w) + (v6.w + v7.w));
    }
    for (; j + 3 < e; j += 4) {
        int s0 = csr_src[j + 0], s1 = csr_src[j + 1], s2 = csr_src[j + 2], s3 = csr_src[j + 3];
        float4 v0 = x4[s0 * 32 + c], v1 = x4[s1 * 32 + c], v2 = x4[s2 * 32 + c], v3 = x4[s3 * 32 + c];
        acc.x += (v0.x + v1.x) + (v2.x + v3.x);
        acc.y += (v0.y + v1.y) + (v2.y + v3.y);
        acc.z += (v0.z + v1.z) + (v2.z + v3.z);
        acc.w += (v0.w + v1.w) + (v2.w + v3.w);
    }
    for (; j < e; ++j) {
        int s = csr_src[j];
        float4 v = x4[s * 32 + c];
        acc.x += v.x; acc.y += v.y; acc.z += v.z; acc.w += v.w;
    }
    acc.x = fmaxf(acc.x, 0.f); acc.y = fmaxf(acc.y, 0.f);
    acc.z = fmaxf(acc.z, 0.f); acc.w = fmaxf(acc.w, 0.f);
    ((float4*)out)[node * 32 + c] = acc;
}

// ---- fallback path kernels (B=1 cursor CSR), proven round 3-5 ------------
__global__ void hist_kernel(const int* __restrict__ dst, int* __restrict__ deg, int E) {
    int i = (blockIdx.x * blockDim.x + threadIdx.x) * 4;
    if (i + 3 < E) {
        int4 d = *(const int4*)&dst[i];
        atomicAdd(&deg[d.x], 1); atomicAdd(&deg[d.y], 1);
        atomicAdd(&deg[d.z], 1); atomicAdd(&deg[d.w], 1);
    } else {
        for (int k = i; k < E; ++k) atomicAdd(&deg[dst[k]], 1);
    }
}

__global__ void reorder_kernel(const int* __restrict__ src, const int* __restrict__ dst,
                               int* __restrict__ cursor, int* __restrict__ csr_src, int E) {
    int i = (blockIdx.x * blockDim.x + threadIdx.x) * 4;
    if (i + 3 < E) {
        int4 s = *(const int4*)&src[i];
        int4 d = *(const int4*)&dst[i];
        csr_src[atomicAdd(&cursor[d.x], 1)] = s.x;
        csr_src[atomicAdd(&cursor[d.y], 1)] = s.y;
        csr_src[atomicAdd(&cursor[d.z], 1)] = s.z;
        csr_src[atomicAdd(&cursor[d.w], 1)] = s.w;
    } else {
        for (int k = i; k < E; ++k) csr_src[atomicAdd(&cursor[dst[k]], 1)] = src[k];
    }
}

// ---- launch --------------------------------------------------------------
extern "C" void kernel_launch(void* const* d_in, const int* in_sizes, int n_in,
                              void* d_out, int out_size, void* d_ws, size_t ws_size,
                              hipStream_t stream) {
    const float* x  = (const float*)d_in[0];
    const int*   ei = (const int*)d_in[1];     // [2, E]: src row then dst row
    float* out = (float*)d_out;

    int N = in_sizes[0] / F;          // 100000
    int E = in_sizes[1] / 2;          // 1600000
    const int* src = ei;
    const int* dst = ei + E;

    int P = (N + BK_NODES - 1) >> BK_SHIFT;            // 1563
    int nblkA = (E + EB_CHUNK - 1) >> EB_LOG;          // 391
    int M2 = P * nblkA;                                // 611133

    char* ws = (char*)d_ws;
    int* counts_T = (int*)ws;                          // M2
    int* offs2    = counts_T + align4i(M2);            // M2+1
    int* ebuf     = offs2 + align4i(M2 + 1);           // E
    int* csr_src  = ebuf + align4i(E);                 // E
    int* offs     = csr_src + align4i(E);              // N+1
    int* bsum     = offs + align4i(N + 1);             // 1024
    int* bpref    = bsum + 1024;                       // 1024
    size_t need = (size_t)((char*)(bpref + 1024) - ws);

    int gth = N * 32;

    if (P <= P_MAX && ws_size >= need) {
        int nB = (M2 + SCAN_CHUNK - 1) / SCAN_CHUNK;   // 150 (<=1024)
        part_hist<<<nblkA, 256, 0, stream>>>(dst, counts_T, E, nblkA, P);
        scan_partial<<<nB, SCAN_T, 0, stream>>>(counts_T, bsum, M2);
        scan_mid<<<1, 1024, 0, stream>>>(bsum, bpref, offs2, nB, M2);
        scan_write<<<nB, SCAN_T, 0, stream>>>(counts_T, bpref, offs2, nullptr, M2);
        part_scatter<<<nblkA, 256, 0, stream>>>(src, dst, offs2, ebuf, E, nblkA, P);
        bucket_csr<<<P, 256, 0, stream>>>(ebuf, offs2, offs, csr_src, N, E, nblkA);
        gather_kernel<<<(gth + 255) / 256, 256, 0, stream>>>(x, offs, csr_src, out, N);
    } else {
        // fallback: B=1 cursor CSR + gather
        int* deg      = (int*)ws;                      // N
        int* fb_offs  = deg + align4i(N);              // N+1
        int* fb_csr   = fb_offs + align4i(N + 1);      // E
        int* cursor   = fb_csr + align4i(E);           // N
        int* fb_bsum  = cursor + align4i(N);
        int* fb_bpref = fb_bsum + 1024;
        int nB = (N + SCAN_CHUNK - 1) / SCAN_CHUNK;
        int eb = (E / 4 + 255) / 256 + 1;
        hipMemsetAsync(deg, 0, (size_t)N * sizeof(int), stream);
        hist_kernel<<<eb, 256, 0, stream>>>(dst, deg, E);
        scan_partial<<<nB, SCAN_T, 0, stream>>>(deg, fb_bsum, N);
        scan_mid<<<1, 1024, 0, stream>>>(fb_bsum, fb_bpref, fb_offs, nB, N);
        scan_write<<<nB, SCAN_T, 0, stream>>>(deg, fb_bpref, fb_offs, cursor, N);
        reorder_kernel<<<eb, 256, 0, stream>>>(src, dst, cursor, fb_csr, E);
        gather_kernel<<<(gth + 255) / 256, 256, 0, stream>>>(x, fb_offs, fb_csr, out, N);
    }
}

// Round 11
// 246.800 us; speedup vs baseline: 5.2938x; 1.0442x over previous
//
#include <hip/hip_runtime.h>

#define F 128
#define SCAN_T 256
#define SCAN_ELEMS 16
#define SCAN_CHUNK (SCAN_T * SCAN_ELEMS)   // 4096 per scan block

#define EB_LOG   13
#define EB_CHUNK 8192                      // edges per partition block
#define BK_SHIFT 8
#define BK_NODES 256                       // nodes per bucket
#define P_MAX    1024                      // max buckets (N <= 262144)

static inline int align4i(int n) { return (n + 3) & ~3; }

// ---- pass A: per-block LDS histogram over dst buckets --------------------
__global__ void part_hist(const int* __restrict__ dst, int* __restrict__ counts_T,
                          int E, int nblkA, int P) {
    __shared__ int hist[P_MAX];
    int b = blockIdx.x, tid = threadIdx.x;
    for (int i = tid; i < P; i += 256) hist[i] = 0;
    __syncthreads();
    int base_e = b << EB_LOG;
#pragma unroll
    for (int q = 0; q < 8; ++q) {
        int i = base_e + (q * 256 + tid) * 4;
        if (i + 3 < E) {
            int4 d = *(const int4*)&dst[i];
            atomicAdd(&hist[d.x >> BK_SHIFT], 1);
            atomicAdd(&hist[d.y >> BK_SHIFT], 1);
            atomicAdd(&hist[d.z >> BK_SHIFT], 1);
            atomicAdd(&hist[d.w >> BK_SHIFT], 1);
        } else {
            for (int k = i; k < E && k < i + 4; ++k)
                atomicAdd(&hist[dst[k] >> BK_SHIFT], 1);
        }
    }
    __syncthreads();
    for (int i = tid; i < P; i += 256) counts_T[i * nblkA + b] = hist[i];
}

// ---- 3-level scan (proven) ----------------------------------------------
__global__ void scan_partial(const int* __restrict__ deg, int* __restrict__ bsum, int M) {
    int base = blockIdx.x * SCAN_CHUNK + threadIdx.x * SCAN_ELEMS;
    int s = 0;
    if (base + SCAN_ELEMS - 1 < M) {
#pragma unroll
        for (int q = 0; q < SCAN_ELEMS / 4; ++q) {
            int4 v = *(const int4*)&deg[base + q * 4];
            s += v.x + v.y + v.z + v.w;
        }
    } else {
        for (int i = base; i < M; ++i) s += deg[i];
    }
    for (int off = 32; off; off >>= 1) s += __shfl_down(s, off);
    __shared__ int wt[4];
    int wid = threadIdx.x >> 6;
    if ((threadIdx.x & 63) == 0) wt[wid] = s;
    __syncthreads();
    if (threadIdx.x == 0) bsum[blockIdx.x] = wt[0] + wt[1] + wt[2] + wt[3];
}

__global__ void __launch_bounds__(1024)
scan_mid(const int* __restrict__ bsum, int* __restrict__ bpref,
         int* __restrict__ offs, int nB, int M) {
    __shared__ int sh[1024];
    int t = threadIdx.x;
    int v = (t < nB) ? bsum[t] : 0;
    sh[t] = v;
    __syncthreads();
    for (int off = 1; off < 1024; off <<= 1) {
        int u = (t >= off) ? sh[t - off] : 0;
        __syncthreads();
        sh[t] += u;
        __syncthreads();
    }
    if (t < nB) bpref[t] = sh[t] - v;          // exclusive
    if (t == 1023) offs[M] = sh[1023];         // total = E
}

__global__ void scan_write(const int* __restrict__ deg, const int* __restrict__ bpref,
                           int* __restrict__ offs, int* __restrict__ cursor, int M) {
    int tid = threadIdx.x;
    int base = blockIdx.x * SCAN_CHUNK + tid * SCAN_ELEMS;
    int v[SCAN_ELEMS];
    int s = 0;
    bool full = (base + SCAN_ELEMS - 1 < M);
    if (full) {
#pragma unroll
        for (int q = 0; q < SCAN_ELEMS / 4; ++q) {
            int4 w = *(const int4*)&deg[base + q * 4];
            v[q * 4 + 0] = w.x; v[q * 4 + 1] = w.y; v[q * 4 + 2] = w.z; v[q * 4 + 3] = w.w;
            s += w.x + w.y + w.z + w.w;
        }
    } else {
#pragma unroll
        for (int k = 0; k < SCAN_ELEMS; ++k) {
            int i = base + k;
            v[k] = (i < M) ? deg[i] : 0;
            s += v[k];
        }
    }
    int inc = s;
    int lane = tid & 63, wid = tid >> 6;
    for (int off = 1; off < 64; off <<= 1) {
        int u = __shfl_up(inc, off);
        if (lane >= off) inc += u;
    }
    __shared__ int wt[4];
    if (lane == 63) wt[wid] = inc;
    __syncthreads();
    int wbase = 0;
    for (int w = 0; w < wid; ++w) wbase += wt[w];
    int run = bpref[blockIdx.x] + wbase + (inc - s);
    if (full) {
#pragma unroll
        for (int q = 0; q < SCAN_ELEMS / 4; ++q) {
            int4 r;
            r.x = run; run += v[q * 4 + 0];
            r.y = run; run += v[q * 4 + 1];
            r.z = run; run += v[q * 4 + 2];
            r.w = run; run += v[q * 4 + 3];
            *(int4*)&offs[base + q * 4] = r;
            if (cursor) *(int4*)&cursor[base + q * 4] = r;
        }
    } else {
#pragma unroll
        for (int k = 0; k < SCAN_ELEMS; ++k) {
            int i = base + k;
            if (i < M) {
                offs[i] = run;
                if (cursor) cursor[i] = run;
                run += v[k];
            }
        }
    }
}

// ---- pass C: place packed edges grouped by bucket (LDS ranks only) -------
__global__ void part_scatter(const int* __restrict__ src, const int* __restrict__ dst,
                             const int* __restrict__ offs2, int* __restrict__ ebuf,
                             int E, int nblkA, int P) {
    __shared__ int hist[P_MAX];
    __shared__ int base[P_MAX];
    int b = blockIdx.x, tid = threadIdx.x;
    for (int i = tid; i < P; i += 256) {
        hist[i] = 0;
        base[i] = offs2[i * nblkA + b];
    }
    __syncthreads();
    int base_e = b << EB_LOG;
#pragma unroll
    for (int q = 0; q < 8; ++q) {
        int i = base_e + (q * 256 + tid) * 4;
        if (i + 3 < E) {
            int4 s = *(const int4*)&src[i];
            int4 d = *(const int4*)&dst[i];
            int bk, r;
            bk = d.x >> BK_SHIFT; r = atomicAdd(&hist[bk], 1);
            ebuf[base[bk] + r] = (s.x << BK_SHIFT) | (d.x & (BK_NODES - 1));
            bk = d.y >> BK_SHIFT; r = atomicAdd(&hist[bk], 1);
            ebuf[base[bk] + r] = (s.y << BK_SHIFT) | (d.y & (BK_NODES - 1));
            bk = d.z >> BK_SHIFT; r = atomicAdd(&hist[bk], 1);
            ebuf[base[bk] + r] = (s.z << BK_SHIFT) | (d.z & (BK_NODES - 1));
            bk = d.w >> BK_SHIFT; r = atomicAdd(&hist[bk], 1);
            ebuf[base[bk] + r] = (s.w << BK_SHIFT) | (d.w & (BK_NODES - 1));
        } else {
            for (int k = i; k < E && k < i + 4; ++k) {
                int bk = dst[k] >> BK_SHIFT;
                int r = atomicAdd(&hist[bk], 1);
                ebuf[base[bk] + r] = (src[k] << BK_SHIFT) | (dst[k] & (BK_NODES - 1));
            }
        }
    }
}

// ---- pass D: per-bucket LDS node-sort -> per-node CSR --------------------
__global__ void bucket_csr(const int* __restrict__ ebuf, const int* __restrict__ offs2,
                           int* __restrict__ offs, int* __restrict__ csr_src,
                           int N, int E, int nblkA) {
    __shared__ int hist[BK_NODES];
    __shared__ int cur[BK_NODES];
    int p = blockIdx.x, tid = threadIdx.x;
    int node_base = p << BK_SHIFT;
    int nrows = N - node_base; if (nrows > BK_NODES) nrows = BK_NODES;
    int b0 = offs2[p * nblkA];
    int b1 = offs2[(p + 1) * nblkA];          // offs2[M2] = E for the last bucket
    if (tid < BK_NODES) hist[tid] = 0;
    __syncthreads();
    for (int i = b0 + tid; i < b1; i += 256)
        atomicAdd(&hist[ebuf[i] & (BK_NODES - 1)], 1);
    __syncthreads();
    {                                          // 256-entry exclusive scan (4 waves)
        int v = hist[tid];
        int inc = v;
        int lane = tid & 63, wid = tid >> 6;
        for (int off = 1; off < 64; off <<= 1) {
            int u = __shfl_up(inc, off);
            if (lane >= off) inc += u;
        }
        __shared__ int wt[4];
        if (lane == 63) wt[wid] = inc;
        __syncthreads();
        int wbase = 0;
        for (int w = 0; w < wid; ++w) wbase += wt[w];
        int ex = wbase + inc - v;
        cur[tid] = ex;
        if (tid < nrows) offs[node_base + tid] = b0 + ex;
    }
    __syncthreads();
    for (int i = b0 + tid; i < b1; i += 256) {
        int pk = ebuf[i];
        int r = atomicAdd(&cur[pk & (BK_NODES - 1)], 1);
        csr_src[b0 + r] = pk >> BK_SHIFT;      // placement within ~16KB window: L2-local
    }
    if (p == 0 && tid == 0) offs[N] = E;
}

// ---- phase 2: proven register-accumulate gather + self-loop + relu -------
__global__ void gather_kernel(const float* __restrict__ x, const int* __restrict__ offs,
                              const int* __restrict__ csr_src, float* __restrict__ out, int N) {
    int t = blockIdx.x * blockDim.x + threadIdx.x;
    int node = t >> 5;
    if (node >= N) return;
    int c = t & 31;
    const float4* x4 = (const float4*)x;
    float4 acc = x4[node * 32 + c];            // self-loop term
    int b = offs[node], e = offs[node + 1];
    int j = b;
    for (; j + 7 < e; j += 8) {
        int s0 = csr_src[j + 0], s1 = csr_src[j + 1], s2 = csr_src[j + 2], s3 = csr_src[j + 3];
        int s4 = csr_src[j + 4], s5 = csr_src[j + 5], s6 = csr_src[j + 6], s7 = csr_src[j + 7];
        float4 v0 = x4[s0 * 32 + c], v1 = x4[s1 * 32 + c], v2 = x4[s2 * 32 + c], v3 = x4[s3 * 32 + c];
        float4 v4 = x4[s4 * 32 + c], v5 = x4[s5 * 32 + c], v6 = x4[s6 * 32 + c], v7 = x4[s7 * 32 + c];
        acc.x += (v0.x + v1.x) + (v2.x + v3.x) + ((v4.x + v5.x) + (v6.x + v7.x));
        acc.y += (v0.y + v1.y) + (v2.y + v3.y) + ((v4.y + v5.y) + (v6.y + v7.y));
        acc.z += (v0.z + v1.z) + (v2.z + v3.z) + ((v4.z + v5.z) + (v6.z + v7.z));
        acc.w += (v0.w + v1.w) + (v2.w + v3.w) + ((v4.w + v5.w) + (v6.w + v7.w));
    }
    for (; j + 3 < e; j += 4) {
        int s0 = csr_src[j + 0], s1 = csr_src[j + 1], s2 = csr_src[j + 2], s3 = csr_src[j + 3];
        float4 v0 = x4[s0 * 32 + c], v1 = x4[s1 * 32 + c], v2 = x4[s2 * 32 + c], v3 = x4[s3 * 32 + c];
        acc.x += (v0.x + v1.x) + (v2.x + v3.x);
        acc.y += (v0.y + v1.y) + (v2.y + v3.y);
        acc.z += (v0.z + v1.z) + (v2.z + v3.z);
        acc.w += (v0.w + v1.w) + (v2.w + v3.w);
    }
    for (; j < e; ++j) {
        int s = csr_src[j];
        float4 v = x4[s * 32 + c];
        acc.x += v.x; acc.y += v.y; acc.z += v.z; acc.w += v.w;
    }
    acc.x = fmaxf(acc.x, 0.f); acc.y = fmaxf(acc.y, 0.f);
    acc.z = fmaxf(acc.z, 0.f); acc.w = fmaxf(acc.w, 0.f);
    ((float4*)out)[node * 32 + c] = acc;
}

// ---- fallback path kernels (B=1 cursor CSR), proven round 3-5 ------------
__global__ void hist_kernel(const int* __restrict__ dst, int* __restrict__ deg, int E) {
    int i = (blockIdx.x * blockDim.x + threadIdx.x) * 4;
    if (i + 3 < E) {
        int4 d = *(const int4*)&dst[i];
        atomicAdd(&deg[d.x], 1); atomicAdd(&deg[d.y], 1);
        atomicAdd(&deg[d.z], 1); atomicAdd(&deg[d.w], 1);
    } else {
        for (int k = i; k < E; ++k) atomicAdd(&deg[dst[k]], 1);
    }
}

__global__ void reorder_kernel(const int* __restrict__ src, const int* __restrict__ dst,
                               int* __restrict__ cursor, int* __restrict__ csr_src, int E) {
    int i = (blockIdx.x * blockDim.x + threadIdx.x) * 4;
    if (i + 3 < E) {
        int4 s = *(const int4*)&src[i];
        int4 d = *(const int4*)&dst[i];
        csr_src[atomicAdd(&cursor[d.x], 1)] = s.x;
        csr_src[atomicAdd(&cursor[d.y], 1)] = s.y;
        csr_src[atomicAdd(&cursor[d.z], 1)] = s.z;
        csr_src[atomicAdd(&cursor[d.w], 1)] = s.w;
    } else {
        for (int k = i; k < E; ++k) csr_src[atomicAdd(&cursor[dst[k]], 1)] = src[k];
    }
}

// ---- launch --------------------------------------------------------------
extern "C" void kernel_launch(void* const* d_in, const int* in_sizes, int n_in,
                              void* d_out, int out_size, void* d_ws, size_t ws_size,
                              hipStream_t stream) {
    const float* x  = (const float*)d_in[0];
    const int*   ei = (const int*)d_in[1];     // [2, E]: src row then dst row
    float* out = (float*)d_out;

    int N = in_sizes[0] / F;          // 100000
    int E = in_sizes[1] / 2;          // 1600000
    const int* src = ei;
    const int* dst = ei + E;

    int P = (N + BK_NODES - 1) >> BK_SHIFT;            // 391
    int nblkA = (E + EB_CHUNK - 1) >> EB_LOG;          // 196
    int M2 = P * nblkA;                                // 76636

    char* ws = (char*)d_ws;
    int* counts_T = (int*)ws;                          // M2
    int* offs2    = counts_T + align4i(M2);            // M2+1
    int* ebuf     = offs2 + align4i(M2 + 1);           // E
    int* csr_src  = ebuf + align4i(E);                 // E
    int* offs     = csr_src + align4i(E);              // N+1
    int* bsum     = offs + align4i(N + 1);             // 1024
    int* bpref    = bsum + 1024;                       // 1024
    size_t need = (size_t)((char*)(bpref + 1024) - ws);

    int gth = N * 32;

    if (P <= P_MAX && ws_size >= need) {
        int nB = (M2 + SCAN_CHUNK - 1) / SCAN_CHUNK;   // 19 (<=1024)
        part_hist<<<nblkA, 256, 0, stream>>>(dst, counts_T, E, nblkA, P);
        scan_partial<<<nB, SCAN_T, 0, stream>>>(counts_T, bsum, M2);
        scan_mid<<<1, 1024, 0, stream>>>(bsum, bpref, offs2, nB, M2);
        scan_write<<<nB, SCAN_T, 0, stream>>>(counts_T, bpref, offs2, nullptr, M2);
        part_scatter<<<nblkA, 256, 0, stream>>>(src, dst, offs2, ebuf, E, nblkA, P);
        bucket_csr<<<P, 256, 0, stream>>>(ebuf, offs2, offs, csr_src, N, E, nblkA);
        gather_kernel<<<(gth + 255) / 256, 256, 0, stream>>>(x, offs, csr_src, out, N);
    } else {
        // fallback: B=1 cursor CSR + gather
        int* deg      = (int*)ws;                      // N
        int* fb_offs  = deg + align4i(N);              // N+1
        int* fb_csr   = fb_offs + align4i(N + 1);      // E
        int* cursor   = fb_csr + align4i(E);           // N
        int* fb_bsum  = cursor + align4i(N);
        int* fb_bpref = fb_bsum + 1024;
        int nB = (N + SCAN_CHUNK - 1) / SCAN_CHUNK;
        int eb = (E / 4 + 255) / 256 + 1;
        hipMemsetAsync(deg, 0, (size_t)N * sizeof(int), stream);
        hist_kernel<<<eb, 256, 0, stream>>>(dst, deg, E);
        scan_partial<<<nB, SCAN_T, 0, stream>>>(deg, fb_bsum, N);
        scan_mid<<<1, 1024, 0, stream>>>(fb_bsum, fb_bpref, fb_offs, nB, N);
        scan_write<<<nB, SCAN_T, 0, stream>>>(deg, fb_bpref, fb_offs, cursor, N);
        reorder_kernel<<<eb, 256, 0, stream>>>(src, dst, cursor, fb_csr, E);
        gather_kernel<<<(gth + 255) / 256, 256, 0, stream>>>(x, fb_offs, fb_csr, out, N);
    }
}